// Round 1
// baseline (27459.741 us; speedup 1.0000x reference)
//
#include <hip/hip_runtime.h>
#include <math.h>

#define Bb 128
#define Nn 100
#define Ee 512
#define Hh 8
#define DHd 64
#define FFf 2048
#define Ll 6
#define STEPS 150

// ---------------------------------------------------------------------------
// Generic tiled fp32 GEMM: C[M,N] = A[M,K] @ B[K,N]  (+bias, relu, split-K)
// B can be two stacked row blocks (B1 rows [0,splitB), B2 rows [splitB,K)) --
// used to fuse ctx@Wih + h@Whh into one GEMM.
// SPLIT: blockIdx.z selects a K chunk; partial written to C + z*M*ldc (no bias).
// ---------------------------------------------------------------------------
template<int BM, int BN, int BK, int TM, int TN, bool RELU, bool BIAS, bool SPLIT>
__global__ __launch_bounds__(256) void gemm_k(
    const float* __restrict__ A, int lda,
    const float* __restrict__ B1, const float* __restrict__ B2, int splitB, int ldb,
    float* __restrict__ C, int ldc,
    const float* __restrict__ bias,
    int M, int N, int K, int kChunk)
{
  __shared__ __align__(16) float As[BK][BM + 4];
  __shared__ __align__(16) float Bs[BK][BN + 4];
  const int tid = threadIdx.x;
  const int m0 = blockIdx.y * BM;
  const int n0 = blockIdx.x * BN;
  const int k0 = SPLIT ? blockIdx.z * kChunk : 0;
  const int kEnd = SPLIT ? (k0 + kChunk) : K;
  constexpr int TCOLS = BN / TN;
  const int tm = tid / TCOLS;
  const int tn = tid % TCOLS;
  float acc[TM][TN];
#pragma unroll
  for (int i = 0; i < TM; ++i)
#pragma unroll
    for (int j = 0; j < TN; ++j) acc[i][j] = 0.f;

  for (int kt = k0; kt < kEnd; kt += BK) {
    constexpr int A4 = BM * BK / 4;
    for (int c = tid; c < A4; c += 256) {
      int mm = c / (BK / 4);
      int k4 = (c % (BK / 4)) * 4;
      float4 av = *(const float4*)(A + (size_t)(m0 + mm) * lda + kt + k4);
      As[k4 + 0][mm] = av.x;
      As[k4 + 1][mm] = av.y;
      As[k4 + 2][mm] = av.z;
      As[k4 + 3][mm] = av.w;
    }
    constexpr int B4 = BK * BN / 4;
    for (int c = tid; c < B4; c += 256) {
      int kk = c / (BN / 4);
      int n4 = (c % (BN / 4)) * 4;
      int kg = kt + kk;
      const float* Brow = (kg < splitB) ? (B1 + (size_t)kg * ldb)
                                        : (B2 + (size_t)(kg - splitB) * ldb);
      *(float4*)&Bs[kk][n4] = *(const float4*)(Brow + n0 + n4);
    }
    __syncthreads();
#pragma unroll
    for (int kk = 0; kk < BK; ++kk) {
      float a[TM], b[TN];
#pragma unroll
      for (int i = 0; i < TM; ++i) a[i] = As[kk][tm * TM + i];
#pragma unroll
      for (int j = 0; j < TN; ++j) b[j] = Bs[kk][tn * TN + j];
#pragma unroll
      for (int i = 0; i < TM; ++i)
#pragma unroll
        for (int j = 0; j < TN; ++j)
          acc[i][j] += a[i] * b[j];
    }
    __syncthreads();
  }

  float* Cout = C + (SPLIT ? (size_t)blockIdx.z * (size_t)M * ldc : (size_t)0);
#pragma unroll
  for (int i = 0; i < TM; ++i) {
    int m = m0 + tm * TM + i;
#pragma unroll
    for (int j = 0; j < TN; j += 4) {
      int n = n0 + tn * TN + j;
      float r0 = acc[i][j + 0], r1 = acc[i][j + 1], r2 = acc[i][j + 2], r3 = acc[i][j + 3];
      if (BIAS) { r0 += bias[n + 0]; r1 += bias[n + 1]; r2 += bias[n + 2]; r3 += bias[n + 3]; }
      if (RELU) { r0 = fmaxf(r0, 0.f); r1 = fmaxf(r1, 0.f); r2 = fmaxf(r2, 0.f); r3 = fmaxf(r3, 0.f); }
      float4 r; r.x = r0; r.y = r1; r.z = r2; r.w = r3;
      *(float4*)(Cout + (size_t)m * ldc + n) = r;
    }
  }
}

// ---------------------------------------------------------------------------
// x = node_features @ in_w + in_b + pe   (one thread per output element)
// ---------------------------------------------------------------------------
__global__ __launch_bounds__(256) void input_proj_k(
    const float* __restrict__ nf, const float* __restrict__ inw,
    const float* __restrict__ inb, const float* __restrict__ pe,
    float* __restrict__ x)
{
  int idx = blockIdx.x * 256 + threadIdx.x;   // < 12800*512
  int bn = idx >> 9, e = idx & 511;
  int n = bn - (bn / Nn) * Nn;
  const float* fr = nf + (size_t)bn * 8;
  float s = inb[e] + pe[(size_t)n * 512 + e];
#pragma unroll
  for (int i = 0; i < 8; ++i) s += fr[i] * inw[(size_t)i * 512 + e];
  x[idx] = s;
}

// ---------------------------------------------------------------------------
// Residual + LayerNorm over rows of 512: out = LN(xin + yin) * g + b
// ---------------------------------------------------------------------------
__global__ __launch_bounds__(256) void ln_k(
    const float* __restrict__ xin, const float* __restrict__ yin,
    const float* __restrict__ g, const float* __restrict__ bb,
    float* __restrict__ out)
{
  int row = blockIdx.x, t = threadIdx.x;
  __shared__ float red[256];
  size_t base = (size_t)row * 512;
  float v0 = xin[base + t] + yin[base + t];
  float v1 = xin[base + 256 + t] + yin[base + 256 + t];
  red[t] = v0 + v1;
  __syncthreads();
  for (int o = 128; o > 0; o >>= 1) { if (t < o) red[t] += red[t + o]; __syncthreads(); }
  float mu = red[0] * (1.f / 512.f);
  __syncthreads();
  float d0 = v0 - mu, d1 = v1 - mu;
  red[t] = d0 * d0 + d1 * d1;
  __syncthreads();
  for (int o = 128; o > 0; o >>= 1) { if (t < o) red[t] += red[t + o]; __syncthreads(); }
  float inv = 1.f / sqrtf(red[0] * (1.f / 512.f) + 1e-5f);
  out[base + t] = d0 * inv * g[t] + bb[t];
  out[base + 256 + t] = d1 * inv * g[t + 256] + bb[t + 256];
}

// ---------------------------------------------------------------------------
// Fused encoder attention per (b,h): S = qk^T/8 -> softmax -> O = P v
// LDS: qs [112][68] & kT [64][113] (phase 1), overlaid by P [100][104] (phase 2).
// v read from global (L1-resident, 25.6 KB/slice). 59.4 KB LDS total.
// ---------------------------------------------------------------------------
__global__ __launch_bounds__(256) void enc_attn_k(
    const float* __restrict__ q, const float* __restrict__ k,
    const float* __restrict__ v, float* __restrict__ o)
{
  __shared__ __align__(16) float smem[14848];
  int bh = blockIdx.x; int b = bh >> 3, h = bh & 7;
  int t = threadIdx.x;
  float* qs = smem;           // stride 68
  float* kT = smem + 7616;    // stride 113
  float* p  = smem;           // stride 104 (overlays qs+kT after phase 1)
  const float* qg = q + ((size_t)b * Nn) * 512 + h * 64;
  const float* kg = k + ((size_t)b * Nn) * 512 + h * 64;
  const float* vg = v + ((size_t)b * Nn) * 512 + h * 64;
  for (int idx = t; idx < 6400; idx += 256) {
    int i = idx >> 6, d = idx & 63;
    qs[i * 68 + d]  = qg[(size_t)i * 512 + d];
    kT[d * 113 + i] = kg[(size_t)i * 512 + d];
  }
  __syncthreads();
  int ti = t >> 4, tj = t & 15;
  int i0 = ti * 7, j0 = tj * 7;
  float s[7][7];
#pragma unroll
  for (int r = 0; r < 7; ++r)
#pragma unroll
    for (int c = 0; c < 7; ++c) s[r][c] = 0.f;
  for (int kk = 0; kk < 64; ++kk) {
    float a[7], bb[7];
#pragma unroll
    for (int r = 0; r < 7; ++r) a[r] = qs[(i0 + r) * 68 + kk];
#pragma unroll
    for (int c = 0; c < 7; ++c) bb[c] = kT[kk * 113 + j0 + c];
#pragma unroll
    for (int r = 0; r < 7; ++r)
#pragma unroll
      for (int c = 0; c < 7; ++c) s[r][c] += a[r] * bb[c];
  }
  __syncthreads();
#pragma unroll
  for (int r = 0; r < 7; ++r)
#pragma unroll
    for (int c = 0; c < 7; ++c) {
      int i = i0 + r, j = j0 + c;
      if (i < Nn && j < Nn) p[i * 104 + j] = s[r][c] * 0.125f;
    }
  __syncthreads();
  // softmax: one wave per row
  int w = t >> 6, lane = t & 63;
  for (int i = w; i < Nn; i += 4) {
    float x0 = p[i * 104 + lane];
    float x1 = (lane < 36) ? p[i * 104 + 64 + lane] : -3.4e38f;
    float mx = fmaxf(x0, x1);
    for (int msk = 32; msk; msk >>= 1) mx = fmaxf(mx, __shfl_xor(mx, msk));
    float e0 = expf(x0 - mx);
    float e1 = (lane < 36) ? expf(x1 - mx) : 0.f;
    float ss = e0 + e1;
    for (int msk = 32; msk; msk >>= 1) ss += __shfl_xor(ss, msk);
    p[i * 104 + lane] = e0 / ss;
    if (lane < 36) p[i * 104 + 64 + lane] = e1 / ss;
  }
  __syncthreads();
  // O = P @ V, v from global
  int d0 = tj * 4;
  float oa[7][4];
#pragma unroll
  for (int r = 0; r < 7; ++r)
#pragma unroll
    for (int c = 0; c < 4; ++c) oa[r][c] = 0.f;
  for (int j = 0; j < Nn; ++j) {
    float pr[7];
#pragma unroll
    for (int r = 0; r < 7; ++r) pr[r] = p[(i0 + r) * 104 + j];
    float4 vv = *(const float4*)(vg + (size_t)j * 512 + d0);
#pragma unroll
    for (int r = 0; r < 7; ++r) {
      oa[r][0] += pr[r] * vv.x; oa[r][1] += pr[r] * vv.y;
      oa[r][2] += pr[r] * vv.z; oa[r][3] += pr[r] * vv.w;
    }
  }
  float* og = o + ((size_t)b * Nn) * 512 + h * 64;
#pragma unroll
  for (int r = 0; r < 7; ++r)
    if (i0 + r < Nn) {
      float4 w4; w4.x = oa[r][0]; w4.y = oa[r][1]; w4.z = oa[r][2]; w4.w = oa[r][3];
      *(float4*)(og + (size_t)(i0 + r) * 512 + d0) = w4;
    }
}

// ---------------------------------------------------------------------------
// Decode: init state.  ctx = mean(node_emb, axis=1); h=c=0; flags=0; logps[150]=0
// ---------------------------------------------------------------------------
__global__ __launch_bounds__(256) void init_k(
    const float* __restrict__ emb, float* __restrict__ ctxh, float* __restrict__ cbuf,
    int* visited, int* ucount, int* complete, int* allvis, int* first, int* prev,
    float* out)
{
  int b = blockIdx.x, t = threadIdx.x;
#pragma unroll
  for (int r = 0; r < 2; ++r) {
    int e = t + 256 * r;
    float s = 0.f;
    for (int i = 0; i < Nn; ++i) s += emb[((size_t)b * Nn + i) * 512 + e];
    ctxh[(size_t)b * 1024 + e] = s / 100.f;
    ctxh[(size_t)b * 1024 + 512 + e] = 0.f;
    cbuf[(size_t)b * 512 + e] = 0.f;
  }
  if (t < Nn) visited[b * Nn + t] = 0;
  if (t == 0) {
    ucount[b] = 0; complete[b] = 0; allvis[b] = 0; first[b] = 0; prev[b] = 0;
    out[150 * Bb + b] = 0.f;   // logps final row
  }
}

// ---------------------------------------------------------------------------
// LSTM pointwise + done-gate + complete update.  gates from 2 split-K partials.
// partial 0 = ctx@Wih, partial 1 = h@Whh (K-chunk boundary == ctx|h boundary).
// ---------------------------------------------------------------------------
__device__ __forceinline__ float sigm(float x) { return 1.f / (1.f + expf(-x)); }

__global__ __launch_bounds__(256) void lstm_pw_k(
    const float* __restrict__ gP, const float* __restrict__ bih, const float* __restrict__ bhh,
    float* __restrict__ ctxh, float* __restrict__ cbuf,
    const float* __restrict__ done_w, const float* __restrict__ done_b,
    int* complete, const int* ucount, int step)
{
  int b = blockIdx.x, t = threadIdx.x;
  __shared__ float red[256];
  const float* g0 = gP + (size_t)b * 2048;
  const float* g1 = gP + 262144 + (size_t)b * 2048;
  float dsum = 0.f;
#pragma unroll
  for (int r = 0; r < 2; ++r) {
    int e = t + 256 * r;
    float ig = g0[e] + g1[e] + bih[e] + bhh[e];
    float fg = g0[e + 512] + g1[e + 512] + bih[e + 512] + bhh[e + 512];
    float gg = g0[e + 1024] + g1[e + 1024] + bih[e + 1024] + bhh[e + 1024];
    float og = g0[e + 1536] + g1[e + 1536] + bih[e + 1536] + bhh[e + 1536];
    float cprev = cbuf[(size_t)b * 512 + e];
    float c2 = sigm(fg) * cprev + sigm(ig) * tanhf(gg);
    float h2 = sigm(og) * tanhf(c2);
    cbuf[(size_t)b * 512 + e] = c2;
    ctxh[(size_t)b * 1024 + 512 + e] = h2;
    dsum += h2 * done_w[e];
  }
  red[t] = dsum; __syncthreads();
  for (int o = 128; o > 0; o >>= 1) { if (t < o) red[t] += red[t + o]; __syncthreads(); }
  if (t == 0) {
    float z = red[0] + done_b[0];
    if (!complete[b] && ucount[b] >= Nn && step >= Nn && z > 0.f) complete[b] = 1;
  }
}

// ---------------------------------------------------------------------------
// Decoder single-query attention per (b,h). q from 8 split-K partials + bias.
// ---------------------------------------------------------------------------
__global__ __launch_bounds__(128) void dec_attn_k(
    const float* __restrict__ qP, const float* __restrict__ bq,
    const float* __restrict__ Kd, const float* __restrict__ Vd,
    float* __restrict__ o)
{
  int bh = blockIdx.x; int b = bh >> 3, h = bh & 7;
  int t = threadIdx.x;
  __shared__ float qh[64];
  __shared__ float p[100];
  __shared__ float red[128];
  if (t < 64) {
    float s = bq[h * 64 + t];
#pragma unroll
    for (int s8 = 0; s8 < 8; ++s8) s += qP[(size_t)s8 * 65536 + (size_t)b * 512 + h * 64 + t];
    qh[t] = s;
  }
  __syncthreads();
  float scv = -3.4e38f;
  if (t < Nn) {
    const float* kr = Kd + ((size_t)b * Nn + t) * 512 + h * 64;
    float s = 0.f;
#pragma unroll
    for (int d = 0; d < 64; ++d) s += qh[d] * kr[d];
    scv = s * 0.125f;
  }
  red[t] = scv; __syncthreads();
  for (int o2 = 64; o2 > 0; o2 >>= 1) { if (t < o2) red[t] = fmaxf(red[t], red[t + o2]); __syncthreads(); }
  float m = red[0]; __syncthreads();
  float ex = (t < Nn) ? expf(scv - m) : 0.f;
  red[t] = ex; __syncthreads();
  for (int o2 = 64; o2 > 0; o2 >>= 1) { if (t < o2) red[t] += red[t + o2]; __syncthreads(); }
  float Z = red[0];
  if (t < Nn) p[t] = ex / Z;
  __syncthreads();
  if (t < 64) {
    float acc = 0.f;
    const float* vr = Vd + (size_t)b * Nn * 512 + h * 64 + t;
    for (int j = 0; j < Nn; ++j) acc += p[j] * vr[(size_t)j * 512];
    o[(size_t)b * 512 + h * 64 + t] = acc;
  }
}

// ---------------------------------------------------------------------------
// Decoder LN:  a = LN(sum(woP partials) + bo) * g + b
// ---------------------------------------------------------------------------
__global__ __launch_bounds__(256) void dec_ln_k(
    const float* __restrict__ woP, const float* __restrict__ bo,
    const float* __restrict__ g, const float* __restrict__ bb,
    float* __restrict__ out)
{
  int b = blockIdx.x, t = threadIdx.x;
  __shared__ float red[256];
  float v[2];
#pragma unroll
  for (int r = 0; r < 2; ++r) {
    int e = t + 256 * r;
    float s = bo[e];
#pragma unroll
    for (int s8 = 0; s8 < 8; ++s8) s += woP[(size_t)s8 * 65536 + (size_t)b * 512 + e];
    v[r] = s;
  }
  red[t] = v[0] + v[1]; __syncthreads();
  for (int o = 128; o > 0; o >>= 1) { if (t < o) red[t] += red[t + o]; __syncthreads(); }
  float mu = red[0] * (1.f / 512.f);
  __syncthreads();
  float d0 = v[0] - mu, d1 = v[1] - mu;
  red[t] = d0 * d0 + d1 * d1; __syncthreads();
  for (int o = 128; o > 0; o >>= 1) { if (t < o) red[t] += red[t + o]; __syncthreads(); }
  float inv = 1.f / sqrtf(red[0] * (1.f / 512.f) + 1e-5f);
  out[(size_t)b * 512 + t] = d0 * inv * g[t] + bb[t];
  out[(size_t)b * 512 + t + 256] = d1 * inv * g[t + 256] + bb[t + 256];
}

// ---------------------------------------------------------------------------
// Scores + penalties/bonus + softmax + argmax + state update + ctx gather.
// One block per batch row; fixed-order reductions (deterministic).
// ---------------------------------------------------------------------------
__global__ __launch_bounds__(256) void select_k(
    const float* __restrict__ pwP, const float* __restrict__ pb,
    const float* __restrict__ emb, const float* __restrict__ ew,
    int* visited, int* ucount, int* complete, int* allvis, int* first, int* prev,
    float* __restrict__ ctxh, float* __restrict__ out,
    const float* __restrict__ sb_p, const float* __restrict__ rp_p, int step)
{
  int b = blockIdx.x, t = threadIdx.x;
  __shared__ float logits[512];
  __shared__ float sc[128];
  __shared__ float red[256];
  __shared__ int redi[256];
#pragma unroll
  for (int r = 0; r < 2; ++r) {
    int e = t + 256 * r;
    float s = pb[e];
#pragma unroll
    for (int s8 = 0; s8 < 8; ++s8) s += pwP[(size_t)s8 * 65536 + (size_t)b * 512 + e];
    logits[e] = s;
  }
  __syncthreads();
  if (t < Nn) {
    const float* er = emb + ((size_t)b * Nn + t) * 512;
    float s = 0.f;
    for (int e = 0; e < 512; ++e) s += logits[e] * er[e];
    int av = allvis[b];
    if (!av && visited[b * Nn + t]) s = rp_p[0];
    if (av) {
      int pv = prev[b];
      float direct = ew[(size_t)b * 10000 + (size_t)pv * 100];
      float via = ew[(size_t)b * 10000 + (size_t)pv * 100 + t] + ew[(size_t)b * 10000 + (size_t)t * 100];
      if (via < direct) s += sb_p[0] * (direct - via) / direct;
    }
    if (complete[b]) s = (t == first[b]) ? 100.f : -1e9f;
    sc[t] = s;
  }
  __syncthreads();
  // argmax (first-max tie-break, matches np.argmax)
  float vv = (t < Nn) ? sc[t] : -3.4e38f;
  int ii = (t < Nn) ? t : 0x7fffffff;
  red[t] = vv; redi[t] = ii;
  __syncthreads();
  for (int o = 128; o > 0; o >>= 1) {
    if (t < o) {
      float v2 = red[t + o]; int i2 = redi[t + o];
      if (v2 > red[t] || (v2 == red[t] && i2 < redi[t])) { red[t] = v2; redi[t] = i2; }
    }
    __syncthreads();
  }
  float m = red[0];
  int curr = redi[0];
  __syncthreads();
  float ex = (t < Nn) ? expf(sc[t] - m) : 0.f;
  red[t] = ex; __syncthreads();
  for (int o = 128; o > 0; o >>= 1) { if (t < o) red[t] += red[t + o]; __syncthreads(); }
  float Z = red[0];
  if (t == 0) {
    float pcur = expf(sc[curr] - m) / Z;
    out[step * Bb + b] = logf(pcur + 1e-10f);
    out[(151 + step) * Bb + b] = (float)curr;
    if (!complete[b]) {
      if (!visited[b * Nn + curr]) ucount[b] = ucount[b] + 1;
      visited[b * Nn + curr] = 1;
    }
    if (ucount[b] >= Nn) allvis[b] = 1;
    if (step == 0) first[b] = curr;
    prev[b] = curr;
  }
  // ctx <- node_emb[b, curr]
  const float* src = emb + ((size_t)b * Nn + curr) * 512;
  ctxh[(size_t)b * 1024 + t] = src[t];
  ctxh[(size_t)b * 1024 + t + 256] = src[t + 256];
}

// tours final row
__global__ void final_k(const int* complete, const int* first, float* out)
{
  int b = threadIdx.x;
  out[(151 + 150) * Bb + b] = complete[b] ? 0.f : (float)first[b];
}

// ---------------------------------------------------------------------------
extern "C" void kernel_launch(void* const* d_in, const int* in_sizes, int n_in,
                              void* d_out, int out_size, void* d_ws, size_t ws_size,
                              hipStream_t stream)
{
  // inputs (setup_inputs dict order)
  const float* nf      = (const float*)d_in[0];
  const float* ew      = (const float*)d_in[1];
  const float* pe      = (const float*)d_in[2];
  const float* in_w    = (const float*)d_in[3];
  const float* in_b    = (const float*)d_in[4];
  const float* enc_wq  = (const float*)d_in[5];
  const float* enc_wk  = (const float*)d_in[6];
  const float* enc_wv  = (const float*)d_in[7];
  const float* enc_wo  = (const float*)d_in[8];
  const float* enc_bq  = (const float*)d_in[9];
  const float* enc_bk  = (const float*)d_in[10];
  const float* enc_bv  = (const float*)d_in[11];
  const float* enc_bo  = (const float*)d_in[12];
  const float* enc_w1  = (const float*)d_in[13];
  const float* enc_b1  = (const float*)d_in[14];
  const float* enc_w2  = (const float*)d_in[15];
  const float* enc_b2  = (const float*)d_in[16];
  const float* ln1g    = (const float*)d_in[17];
  const float* ln1b    = (const float*)d_in[18];
  const float* ln2g    = (const float*)d_in[19];
  const float* ln2b    = (const float*)d_in[20];
  const float* wih     = (const float*)d_in[21];
  const float* whh     = (const float*)d_in[22];
  const float* bih     = (const float*)d_in[23];
  const float* bhh     = (const float*)d_in[24];
  const float* dwq     = (const float*)d_in[25];
  const float* dwk     = (const float*)d_in[26];
  const float* dwv     = (const float*)d_in[27];
  const float* dwo     = (const float*)d_in[28];
  const float* dpw     = (const float*)d_in[29];
  const float* dbq     = (const float*)d_in[30];
  const float* dbk     = (const float*)d_in[31];
  const float* dbv     = (const float*)d_in[32];
  const float* dbo     = (const float*)d_in[33];
  const float* dpb     = (const float*)d_in[34];
  const float* dlng    = (const float*)d_in[35];
  const float* dlnb    = (const float*)d_in[36];
  const float* sbp     = (const float*)d_in[37];
  const float* rpp     = (const float*)d_in[38];
  const float* done_w  = (const float*)d_in[39];
  const float* done_b  = (const float*)d_in[40];
  float* out = (float*)d_out;

  // workspace carve (floats)
  float* ws = (float*)d_ws;
  const size_t SZ = 12800ull * 512;           // 6,553,600
  float* x      = ws;                          // node features / node_emb
  float* xq     = x  + SZ;                     // q / wo-out / ff2-out
  float* xk     = xq + SZ;                     // enc k  -> dec K
  float* xv     = xk + SZ;                     // enc v  -> dec V
  float* xo     = xv + SZ;                     // attn output / dec attn o
  float* ffb    = xo + SZ;                     // 3200 x 2048 FF chunk
  float* ctxh   = ffb + SZ;                    // 128 x 1024  [ctx | h]
  float* cbuf   = ctxh + 131072;               // 128 x 512
  float* gatesP = cbuf + 65536;                // 2 x 128 x 2048
  float* qP     = gatesP + 524288;             // 8 x 128 x 512
  float* woP    = qP + 524288;
  float* pwP    = woP + 524288;
  float* abuf   = pwP + 524288;                // 128 x 512
  int* ivis     = (int*)(abuf + 65536);        // 128 x 100
  int* ucount   = ivis + 12800;
  int* complete = ucount + 128;
  int* allvis   = complete + 128;
  int* first    = allvis + 128;
  int* prev     = first + 128;

  const int BIG = 1 << 30;

  // ---- encoder ----
  input_proj_k<<<25600, 256, 0, stream>>>(nf, in_w, in_b, pe, x);

  for (int l = 0; l < Ll; ++l) {
    const float* wq = enc_wq + (size_t)l * 262144;
    const float* wk = enc_wk + (size_t)l * 262144;
    const float* wv = enc_wv + (size_t)l * 262144;
    const float* wo = enc_wo + (size_t)l * 262144;
    const float* bq = enc_bq + (size_t)l * 512;
    const float* bk = enc_bk + (size_t)l * 512;
    const float* bv = enc_bv + (size_t)l * 512;
    const float* bo = enc_bo + (size_t)l * 512;
    const float* w1 = enc_w1 + (size_t)l * 1048576;
    const float* b1 = enc_b1 + (size_t)l * 2048;
    const float* w2 = enc_w2 + (size_t)l * 1048576;
    const float* b2 = enc_b2 + (size_t)l * 512;

    gemm_k<128,128,16,8,8,false,true,false><<<dim3(4,100,1), 256, 0, stream>>>(
        x, 512, wq, wq, BIG, 512, xq, 512, bq, 12800, 512, 512, 0);
    gemm_k<128,128,16,8,8,false,true,false><<<dim3(4,100,1), 256, 0, stream>>>(
        x, 512, wk, wk, BIG, 512, xk, 512, bk, 12800, 512, 512, 0);
    gemm_k<128,128,16,8,8,false,true,false><<<dim3(4,100,1), 256, 0, stream>>>(
        x, 512, wv, wv, BIG, 512, xv, 512, bv, 12800, 512, 512, 0);
    enc_attn_k<<<1024, 256, 0, stream>>>(xq, xk, xv, xo);
    gemm_k<128,128,16,8,8,false,true,false><<<dim3(4,100,1), 256, 0, stream>>>(
        xo, 512, wo, wo, BIG, 512, xq, 512, bo, 12800, 512, 512, 0);
    ln_k<<<12800, 256, 0, stream>>>(x, xq, ln1g + l * 512, ln1b + l * 512, x);
    for (int c = 0; c < 4; ++c) {
      gemm_k<128,128,16,8,8,true,true,false><<<dim3(16,25,1), 256, 0, stream>>>(
          x + (size_t)c * 3200 * 512, 512, w1, w1, BIG, 2048, ffb, 2048, b1, 3200, 2048, 512, 0);
      gemm_k<128,128,16,8,8,false,true,false><<<dim3(4,25,1), 256, 0, stream>>>(
          ffb, 2048, w2, w2, BIG, 512, xq + (size_t)c * 3200 * 512, 512, b2, 3200, 512, 2048, 0);
    }
    ln_k<<<12800, 256, 0, stream>>>(x, xq, ln2g + l * 512, ln2b + l * 512, x);
  }

  // ---- decode prep: K/V are step-invariant; hoist ----
  gemm_k<128,128,16,8,8,false,true,false><<<dim3(4,100,1), 256, 0, stream>>>(
      x, 512, dwk, dwk, BIG, 512, xk, 512, dbk, 12800, 512, 512, 0);
  gemm_k<128,128,16,8,8,false,true,false><<<dim3(4,100,1), 256, 0, stream>>>(
      x, 512, dwv, dwv, BIG, 512, xv, 512, dbv, 12800, 512, 512, 0);
  init_k<<<128, 256, 0, stream>>>(x, ctxh, cbuf, ivis, ucount, complete, allvis, first, prev, out);

  // ---- decode loop ----
  for (int step = 0; step < STEPS; ++step) {
    // gates = [ctx|h] @ [Wih;Whh]  (split-K 2: chunk boundary == ctx|h boundary)
    gemm_k<32,64,16,2,4,false,false,true><<<dim3(32,4,2), 256, 0, stream>>>(
        ctxh, 1024, wih, whh, 512, 2048, gatesP, 2048, nullptr, 128, 2048, 1024, 512);
    lstm_pw_k<<<128, 256, 0, stream>>>(gatesP, bih, bhh, ctxh, cbuf, done_w, done_b,
                                       complete, ucount, step);
    // q = h2 @ dec_wq (split-K 8)
    gemm_k<32,64,16,2,4,false,false,true><<<dim3(8,4,8), 256, 0, stream>>>(
        ctxh + 512, 1024, dwq, dwq, BIG, 512, qP, 512, nullptr, 128, 512, 512, 64);
    dec_attn_k<<<1024, 128, 0, stream>>>(qP, dbq, xk, xv, xo);
    // o @ dec_wo (split-K 8)
    gemm_k<32,64,16,2,4,false,false,true><<<dim3(8,4,8), 256, 0, stream>>>(
        xo, 512, dwo, dwo, BIG, 512, woP, 512, nullptr, 128, 512, 512, 64);
    dec_ln_k<<<128, 256, 0, stream>>>(woP, dbo, dlng, dlnb, abuf);
    // logits = a @ dec_pw (split-K 8)
    gemm_k<32,64,16,2,4,false,false,true><<<dim3(8,4,8), 256, 0, stream>>>(
        abuf, 512, dpw, dpw, BIG, 512, pwP, 512, nullptr, 128, 512, 512, 64);
    select_k<<<128, 256, 0, stream>>>(pwP, dpb, x, ew, ivis, ucount, complete, allvis,
                                      first, prev, ctxh, out, sbp, rpp, step);
  }
  final_k<<<1, 128, 0, stream>>>(complete, first, out);
}

// Round 2
// 16505.536 us; speedup vs baseline: 1.6637x; 1.6637x over previous
//
#include <hip/hip_runtime.h>
#include <math.h>

#define Bb 128
#define Nn 100
#define Ee 512
#define Hh 8
#define DHd 64
#define FFf 2048
#define Ll 6
#define STEPS 150

typedef _Float16 h8 __attribute__((ext_vector_type(8)));
typedef _Float16 h4 __attribute__((ext_vector_type(4)));
typedef float f4 __attribute__((ext_vector_type(4)));

// ---------------------------------------------------------------------------
// Split-f16 MFMA GEMM.  C[M,N] = A[M,K] @ B[K,N] computed as
// Ah*Bh + Ah*Bl + Al*Bh with f16 hi/lo planes (pre-split inputs).
// A planes: [M][K] f16.  B planes: pre-transposed [N][K] f16.
// Tile 128x128, BK=32, 4 waves (2x2), each wave 4x4 frags of 16x16x32.
// OUTF32: fp32 (+bias,+relu).  else: write f16 hi/lo planes (+bias,+relu).
// SPLITK: blockIdx.z picks K-chunk kc, partial to C + z*Mtot*ldc, no bias.
// ---------------------------------------------------------------------------
template<bool RELU, bool BIAS, bool OUTF32, bool SPLITK>
__global__ __launch_bounds__(256) void mgemm_k(
    const _Float16* __restrict__ Ah, const _Float16* __restrict__ Al, int lda,
    const _Float16* __restrict__ Bh, const _Float16* __restrict__ Bl, int ldb,
    float* __restrict__ C, _Float16* __restrict__ Ch, _Float16* __restrict__ Cl,
    int ldc, const float* __restrict__ bias, int K, int kc, int Mtot)
{
  __shared__ _Float16 sm[4 * 5120];            // 4 planes of 128 x (32+8pad)
  _Float16* sAh = sm;
  _Float16* sAl = sm + 5120;
  _Float16* sBh = sm + 10240;
  _Float16* sBl = sm + 15360;
  const int tid = threadIdx.x;
  const int m0 = blockIdx.y * 128, n0 = blockIdx.x * 128;
  const int k0 = SPLITK ? blockIdx.z * kc : 0;
  const int kEnd = SPLITK ? k0 + kc : K;
  const int lane = tid & 63, wave = tid >> 6;
  const int wm = wave >> 1, wn = wave & 1;
  const int m16 = lane & 15, kg = lane >> 4;
  f4 acc[4][4];
#pragma unroll
  for (int i = 0; i < 4; ++i)
#pragma unroll
    for (int j = 0; j < 4; ++j) acc[i][j] = (f4)0.f;

  for (int kt = k0; kt < kEnd; kt += 32) {
#pragma unroll
    for (int it = 0; it < 2; ++it) {
      int idx = tid + it * 256;                // 512 (row,g) slots
      int row = idx >> 2, g = idx & 3;
      int lo_ = row * 40 + g * 8;
      size_t ga = (size_t)(m0 + row) * lda + kt + g * 8;
      size_t gb = (size_t)(n0 + row) * ldb + kt + g * 8;
      *(h8*)(sAh + lo_) = *(const h8*)(Ah + ga);
      *(h8*)(sAl + lo_) = *(const h8*)(Al + ga);
      *(h8*)(sBh + lo_) = *(const h8*)(Bh + gb);
      *(h8*)(sBl + lo_) = *(const h8*)(Bl + gb);
    }
    __syncthreads();
    h8 a_h[4], a_l[4], b_h[4], b_l[4];
#pragma unroll
    for (int i = 0; i < 4; ++i) {
      int ro = (wm * 64 + i * 16 + m16) * 40 + kg * 8;
      int co = (wn * 64 + i * 16 + m16) * 40 + kg * 8;
      a_h[i] = *(const h8*)(sAh + ro);
      a_l[i] = *(const h8*)(sAl + ro);
      b_h[i] = *(const h8*)(sBh + co);
      b_l[i] = *(const h8*)(sBl + co);
    }
#pragma unroll
    for (int i = 0; i < 4; ++i)
#pragma unroll
      for (int j = 0; j < 4; ++j) {
        acc[i][j] = __builtin_amdgcn_mfma_f32_16x16x32_f16(a_h[i], b_h[j], acc[i][j], 0, 0, 0);
        acc[i][j] = __builtin_amdgcn_mfma_f32_16x16x32_f16(a_h[i], b_l[j], acc[i][j], 0, 0, 0);
        acc[i][j] = __builtin_amdgcn_mfma_f32_16x16x32_f16(a_l[i], b_h[j], acc[i][j], 0, 0, 0);
      }
    __syncthreads();
  }

  float* Cz = OUTF32 ? (C + (SPLITK ? (size_t)blockIdx.z * (size_t)Mtot * ldc : (size_t)0)) : C;
  int rb = m0 + wm * 64 + kg * 4;              // C/D: row=(lane>>4)*4+reg
  int cb = n0 + wn * 64 + m16;                 //      col=lane&15
#pragma unroll
  for (int j = 0; j < 4; ++j) {
    int col = cb + j * 16;
    float bv = BIAS ? bias[col] : 0.f;
#pragma unroll
    for (int i = 0; i < 4; ++i) {
#pragma unroll
      for (int r = 0; r < 4; ++r) {
        float v = acc[i][j][r] + bv;
        if (RELU) v = fmaxf(v, 0.f);
        int row = rb + i * 16 + r;
        if (OUTF32) {
          Cz[(size_t)row * ldc + col] = v;
        } else {
          _Float16 hh = (_Float16)v;
          Ch[(size_t)row * ldc + col] = hh;
          Cl[(size_t)row * ldc + col] = (_Float16)(v - (float)hh);
        }
      }
    }
  }
}

// ---------------------------------------------------------------------------
// Weight transpose + split:  W [K][N] fp32  ->  Th/Tl [N][K] f16
// ---------------------------------------------------------------------------
__global__ __launch_bounds__(256) void wconv_k(
    const float* __restrict__ W, int K, int N,
    _Float16* __restrict__ Th, _Float16* __restrict__ Tl)
{
  __shared__ float t[32][33];
  int n0 = blockIdx.x * 32, k0 = blockIdx.y * 32;
  int tid = threadIdx.x;
  int r = tid >> 3, c4 = (tid & 7) * 4;
  float4 v = *(const float4*)(W + (size_t)(k0 + r) * N + n0 + c4);
  t[r][c4 + 0] = v.x; t[r][c4 + 1] = v.y; t[r][c4 + 2] = v.z; t[r][c4 + 3] = v.w;
  __syncthreads();
  h4 hi, lo;
#pragma unroll
  for (int i = 0; i < 4; ++i) {
    float x = t[c4 + i][r];
    _Float16 hh = (_Float16)x;
    hi[i] = hh;
    lo[i] = (_Float16)(x - (float)hh);
  }
  *(h4*)(Th + (size_t)(n0 + r) * K + k0 + c4) = hi;
  *(h4*)(Tl + (size_t)(n0 + r) * K + k0 + c4) = lo;
}

// FF2 split-K(4) partial reduce + bias, chunk of 3200x512
__global__ __launch_bounds__(256) void reduce4_k(
    const float* __restrict__ P, const float* __restrict__ bias, float* __restrict__ out)
{
  int idx = blockIdx.x * 256 + threadIdx.x;   // < 3200*512
  const size_t S = 3200ull * 512;
  float v = P[idx] + P[idx + S] + P[idx + 2 * S] + P[idx + 3 * S] + bias[idx & 511];
  out[idx] = v;
}

// ---------------------------------------------------------------------------
// x = node_features @ in_w + in_b + pe   (+ f16 hi/lo planes)
// ---------------------------------------------------------------------------
__global__ __launch_bounds__(256) void input_proj_k(
    const float* __restrict__ nf, const float* __restrict__ inw,
    const float* __restrict__ inb, const float* __restrict__ pe,
    float* __restrict__ x, _Float16* __restrict__ xh, _Float16* __restrict__ xl)
{
  int idx = blockIdx.x * 256 + threadIdx.x;   // < 12800*512
  int bn = idx >> 9, e = idx & 511;
  int n = bn - (bn / Nn) * Nn;
  const float* fr = nf + (size_t)bn * 8;
  float s = inb[e] + pe[(size_t)n * 512 + e];
#pragma unroll
  for (int i = 0; i < 8; ++i) s += fr[i] * inw[(size_t)i * 512 + e];
  x[idx] = s;
  _Float16 hh = (_Float16)s;
  xh[idx] = hh;
  xl[idx] = (_Float16)(s - (float)hh);
}

// ---------------------------------------------------------------------------
// Residual + LayerNorm (rows of 512) + f16 hi/lo planes
// ---------------------------------------------------------------------------
__global__ __launch_bounds__(256) void ln_k(
    const float* __restrict__ xin, const float* __restrict__ yin,
    const float* __restrict__ g, const float* __restrict__ bb,
    float* __restrict__ out, _Float16* __restrict__ oh, _Float16* __restrict__ ol)
{
  int row = blockIdx.x, t = threadIdx.x;
  __shared__ float red[256];
  size_t base = (size_t)row * 512;
  float v0 = xin[base + t] + yin[base + t];
  float v1 = xin[base + 256 + t] + yin[base + 256 + t];
  red[t] = v0 + v1;
  __syncthreads();
  for (int o = 128; o > 0; o >>= 1) { if (t < o) red[t] += red[t + o]; __syncthreads(); }
  float mu = red[0] * (1.f / 512.f);
  __syncthreads();
  float d0 = v0 - mu, d1 = v1 - mu;
  red[t] = d0 * d0 + d1 * d1;
  __syncthreads();
  for (int o = 128; o > 0; o >>= 1) { if (t < o) red[t] += red[t + o]; __syncthreads(); }
  float inv = 1.f / sqrtf(red[0] * (1.f / 512.f) + 1e-5f);
  float y0 = d0 * inv * g[t] + bb[t];
  float y1 = d1 * inv * g[t + 256] + bb[t + 256];
  out[base + t] = y0;
  out[base + 256 + t] = y1;
  _Float16 h0 = (_Float16)y0, h1 = (_Float16)y1;
  oh[base + t] = h0;           ol[base + t] = (_Float16)(y0 - (float)h0);
  oh[base + 256 + t] = h1;     ol[base + 256 + t] = (_Float16)(y1 - (float)h1);
}

// ---------------------------------------------------------------------------
// Fused encoder attention per (b,h); output written as f16 hi/lo planes.
// ---------------------------------------------------------------------------
__global__ __launch_bounds__(256) void enc_attn_k(
    const float* __restrict__ q, const float* __restrict__ k,
    const float* __restrict__ v, _Float16* __restrict__ oh, _Float16* __restrict__ ol)
{
  __shared__ __align__(16) float smem[14848];
  int bh = blockIdx.x; int b = bh >> 3, h = bh & 7;
  int t = threadIdx.x;
  float* qs = smem;           // stride 68
  float* kT = smem + 7616;    // stride 113
  float* p  = smem;           // stride 104 (overlay after phase 1)
  const float* qg = q + ((size_t)b * Nn) * 512 + h * 64;
  const float* kg = k + ((size_t)b * Nn) * 512 + h * 64;
  const float* vg = v + ((size_t)b * Nn) * 512 + h * 64;
  for (int idx = t; idx < 6400; idx += 256) {
    int i = idx >> 6, d = idx & 63;
    qs[i * 68 + d]  = qg[(size_t)i * 512 + d];
    kT[d * 113 + i] = kg[(size_t)i * 512 + d];
  }
  __syncthreads();
  int ti = t >> 4, tj = t & 15;
  int i0 = ti * 7, j0 = tj * 7;
  float s[7][7];
#pragma unroll
  for (int r = 0; r < 7; ++r)
#pragma unroll
    for (int c = 0; c < 7; ++c) s[r][c] = 0.f;
  for (int kk = 0; kk < 64; ++kk) {
    float a[7], bb[7];
#pragma unroll
    for (int r = 0; r < 7; ++r) a[r] = qs[(i0 + r) * 68 + kk];
#pragma unroll
    for (int c = 0; c < 7; ++c) bb[c] = kT[kk * 113 + j0 + c];
#pragma unroll
    for (int r = 0; r < 7; ++r)
#pragma unroll
      for (int c = 0; c < 7; ++c) s[r][c] += a[r] * bb[c];
  }
  __syncthreads();
#pragma unroll
  for (int r = 0; r < 7; ++r)
#pragma unroll
    for (int c = 0; c < 7; ++c) {
      int i = i0 + r, j = j0 + c;
      if (i < Nn && j < Nn) p[i * 104 + j] = s[r][c] * 0.125f;
    }
  __syncthreads();
  int w = t >> 6, lane = t & 63;
  for (int i = w; i < Nn; i += 4) {
    float x0 = p[i * 104 + lane];
    float x1 = (lane < 36) ? p[i * 104 + 64 + lane] : -3.4e38f;
    float mx = fmaxf(x0, x1);
    for (int msk = 32; msk; msk >>= 1) mx = fmaxf(mx, __shfl_xor(mx, msk));
    float e0 = expf(x0 - mx);
    float e1 = (lane < 36) ? expf(x1 - mx) : 0.f;
    float ss = e0 + e1;
    for (int msk = 32; msk; msk >>= 1) ss += __shfl_xor(ss, msk);
    p[i * 104 + lane] = e0 / ss;
    if (lane < 36) p[i * 104 + 64 + lane] = e1 / ss;
  }
  __syncthreads();
  int d0 = tj * 4;
  float oa[7][4];
#pragma unroll
  for (int r = 0; r < 7; ++r)
#pragma unroll
    for (int c = 0; c < 4; ++c) oa[r][c] = 0.f;
  for (int j = 0; j < Nn; ++j) {
    float pr[7];
#pragma unroll
    for (int r = 0; r < 7; ++r) pr[r] = p[(i0 + r) * 104 + j];
    float4 vv = *(const float4*)(vg + (size_t)j * 512 + d0);
#pragma unroll
    for (int r = 0; r < 7; ++r) {
      oa[r][0] += pr[r] * vv.x; oa[r][1] += pr[r] * vv.y;
      oa[r][2] += pr[r] * vv.z; oa[r][3] += pr[r] * vv.w;
    }
  }
  size_t ob = ((size_t)b * Nn) * 512 + h * 64 + d0;
#pragma unroll
  for (int r = 0; r < 7; ++r)
    if (i0 + r < Nn) {
      h4 hv, lv;
#pragma unroll
      for (int c = 0; c < 4; ++c) {
        _Float16 hh = (_Float16)oa[r][c];
        hv[c] = hh;
        lv[c] = (_Float16)(oa[r][c] - (float)hh);
      }
      *(h4*)(oh + ob + (size_t)(i0 + r) * 512) = hv;
      *(h4*)(ol + ob + (size_t)(i0 + r) * 512) = lv;
    }
}

// ---------------------------------------------------------------------------
// fp32 tiled GEMM (decode-loop small GEMMs only; split-K partials)
// ---------------------------------------------------------------------------
template<int BM, int BN, int BK, int TM, int TN>
__global__ __launch_bounds__(256) void gemm_k(
    const float* __restrict__ A, int lda,
    const float* __restrict__ B1, const float* __restrict__ B2, int splitB, int ldb,
    float* __restrict__ C, int ldc, int M, int N, int K, int kChunk)
{
  __shared__ __align__(16) float As[BK][BM + 4];
  __shared__ __align__(16) float Bs[BK][BN + 4];
  const int tid = threadIdx.x;
  const int m0 = blockIdx.y * BM;
  const int n0 = blockIdx.x * BN;
  const int k0 = blockIdx.z * kChunk;
  const int kEnd = k0 + kChunk;
  constexpr int TCOLS = BN / TN;
  const int tm = tid / TCOLS;
  const int tn = tid % TCOLS;
  float acc[TM][TN];
#pragma unroll
  for (int i = 0; i < TM; ++i)
#pragma unroll
    for (int j = 0; j < TN; ++j) acc[i][j] = 0.f;

  for (int kt = k0; kt < kEnd; kt += BK) {
    constexpr int A4 = BM * BK / 4;
    for (int c = tid; c < A4; c += 256) {
      int mm = c / (BK / 4);
      int k4 = (c % (BK / 4)) * 4;
      float4 av = *(const float4*)(A + (size_t)(m0 + mm) * lda + kt + k4);
      As[k4 + 0][mm] = av.x;
      As[k4 + 1][mm] = av.y;
      As[k4 + 2][mm] = av.z;
      As[k4 + 3][mm] = av.w;
    }
    constexpr int B4 = BK * BN / 4;
    for (int c = tid; c < B4; c += 256) {
      int kk = c / (BN / 4);
      int n4 = (c % (BN / 4)) * 4;
      int kgi = kt + kk;
      const float* Brow = (kgi < splitB) ? (B1 + (size_t)kgi * ldb)
                                         : (B2 + (size_t)(kgi - splitB) * ldb);
      *(float4*)&Bs[kk][n4] = *(const float4*)(Brow + n0 + n4);
    }
    __syncthreads();
#pragma unroll
    for (int kk = 0; kk < BK; ++kk) {
      float a[TM], b[TN];
#pragma unroll
      for (int i = 0; i < TM; ++i) a[i] = As[kk][tm * TM + i];
#pragma unroll
      for (int j = 0; j < TN; ++j) b[j] = Bs[kk][tn * TN + j];
#pragma unroll
      for (int i = 0; i < TM; ++i)
#pragma unroll
        for (int j = 0; j < TN; ++j)
          acc[i][j] += a[i] * b[j];
    }
    __syncthreads();
  }

  float* Cout = C + (size_t)blockIdx.z * (size_t)M * ldc;
#pragma unroll
  for (int i = 0; i < TM; ++i) {
    int m = m0 + tm * TM + i;
#pragma unroll
    for (int j = 0; j < TN; j += 4) {
      int n = n0 + tn * TN + j;
      float4 r;
      r.x = acc[i][j + 0]; r.y = acc[i][j + 1]; r.z = acc[i][j + 2]; r.w = acc[i][j + 3];
      *(float4*)(Cout + (size_t)m * ldc + n) = r;
    }
  }
}

// ---------------------------------------------------------------------------
__global__ __launch_bounds__(256) void init_k(
    const float* __restrict__ emb, float* __restrict__ ctxh, float* __restrict__ cbuf,
    int* visited, int* ucount, int* complete, int* allvis, int* first, int* prev,
    float* out)
{
  int b = blockIdx.x, t = threadIdx.x;
#pragma unroll
  for (int r = 0; r < 2; ++r) {
    int e = t + 256 * r;
    float s = 0.f;
    for (int i = 0; i < Nn; ++i) s += emb[((size_t)b * Nn + i) * 512 + e];
    ctxh[(size_t)b * 1024 + e] = s / 100.f;
    ctxh[(size_t)b * 1024 + 512 + e] = 0.f;
    cbuf[(size_t)b * 512 + e] = 0.f;
  }
  if (t < Nn) visited[b * Nn + t] = 0;
  if (t == 0) {
    ucount[b] = 0; complete[b] = 0; allvis[b] = 0; first[b] = 0; prev[b] = 0;
    out[150 * Bb + b] = 0.f;
  }
}

__device__ __forceinline__ float sigm(float x) { return 1.f / (1.f + expf(-x)); }

__global__ __launch_bounds__(256) void lstm_pw_k(
    const float* __restrict__ gP, const float* __restrict__ bih, const float* __restrict__ bhh,
    float* __restrict__ ctxh, float* __restrict__ cbuf,
    const float* __restrict__ done_w, const float* __restrict__ done_b,
    int* complete, const int* ucount, int step)
{
  int b = blockIdx.x, t = threadIdx.x;
  __shared__ float red[256];
  const float* g0 = gP + (size_t)b * 2048;
  const float* g1 = gP + 262144 + (size_t)b * 2048;
  float dsum = 0.f;
#pragma unroll
  for (int r = 0; r < 2; ++r) {
    int e = t + 256 * r;
    float ig = g0[e] + g1[e] + bih[e] + bhh[e];
    float fg = g0[e + 512] + g1[e + 512] + bih[e + 512] + bhh[e + 512];
    float gg = g0[e + 1024] + g1[e + 1024] + bih[e + 1024] + bhh[e + 1024];
    float og = g0[e + 1536] + g1[e + 1536] + bih[e + 1536] + bhh[e + 1536];
    float cprev = cbuf[(size_t)b * 512 + e];
    float c2 = sigm(fg) * cprev + sigm(ig) * tanhf(gg);
    float h2 = sigm(og) * tanhf(c2);
    cbuf[(size_t)b * 512 + e] = c2;
    ctxh[(size_t)b * 1024 + 512 + e] = h2;
    dsum += h2 * done_w[e];
  }
  red[t] = dsum; __syncthreads();
  for (int o = 128; o > 0; o >>= 1) { if (t < o) red[t] += red[t + o]; __syncthreads(); }
  if (t == 0) {
    float z = red[0] + done_b[0];
    if (!complete[b] && ucount[b] >= Nn && step >= Nn && z > 0.f) complete[b] = 1;
  }
}

__global__ __launch_bounds__(128) void dec_attn_k(
    const float* __restrict__ qP, const float* __restrict__ bq,
    const float* __restrict__ Kd, const float* __restrict__ Vd,
    float* __restrict__ o)
{
  int bh = blockIdx.x; int b = bh >> 3, h = bh & 7;
  int t = threadIdx.x;
  __shared__ float qh[64];
  __shared__ float p[100];
  __shared__ float red[128];
  if (t < 64) {
    float s = bq[h * 64 + t];
#pragma unroll
    for (int s8 = 0; s8 < 8; ++s8) s += qP[(size_t)s8 * 65536 + (size_t)b * 512 + h * 64 + t];
    qh[t] = s;
  }
  __syncthreads();
  float scv = -3.4e38f;
  if (t < Nn) {
    const float* kr = Kd + ((size_t)b * Nn + t) * 512 + h * 64;
    float s = 0.f;
#pragma unroll
    for (int d = 0; d < 64; ++d) s += qh[d] * kr[d];
    scv = s * 0.125f;
  }
  red[t] = scv; __syncthreads();
  for (int o2 = 64; o2 > 0; o2 >>= 1) { if (t < o2) red[t] = fmaxf(red[t], red[t + o2]); __syncthreads(); }
  float m = red[0]; __syncthreads();
  float ex = (t < Nn) ? expf(scv - m) : 0.f;
  red[t] = ex; __syncthreads();
  for (int o2 = 64; o2 > 0; o2 >>= 1) { if (t < o2) red[t] += red[t + o2]; __syncthreads(); }
  float Z = red[0];
  if (t < Nn) p[t] = ex / Z;
  __syncthreads();
  if (t < 64) {
    float acc = 0.f;
    const float* vr = Vd + (size_t)b * Nn * 512 + h * 64 + t;
    for (int j = 0; j < Nn; ++j) acc += p[j] * vr[(size_t)j * 512];
    o[(size_t)b * 512 + h * 64 + t] = acc;
  }
}

__global__ __launch_bounds__(256) void dec_ln_k(
    const float* __restrict__ woP, const float* __restrict__ bo,
    const float* __restrict__ g, const float* __restrict__ bb,
    float* __restrict__ out)
{
  int b = blockIdx.x, t = threadIdx.x;
  __shared__ float red[256];
  float v[2];
#pragma unroll
  for (int r = 0; r < 2; ++r) {
    int e = t + 256 * r;
    float s = bo[e];
#pragma unroll
    for (int s8 = 0; s8 < 8; ++s8) s += woP[(size_t)s8 * 65536 + (size_t)b * 512 + e];
    v[r] = s;
  }
  red[t] = v[0] + v[1]; __syncthreads();
  for (int o = 128; o > 0; o >>= 1) { if (t < o) red[t] += red[t + o]; __syncthreads(); }
  float mu = red[0] * (1.f / 512.f);
  __syncthreads();
  float d0 = v[0] - mu, d1 = v[1] - mu;
  red[t] = d0 * d0 + d1 * d1; __syncthreads();
  for (int o = 128; o > 0; o >>= 1) { if (t < o) red[t] += red[t + o]; __syncthreads(); }
  float inv = 1.f / sqrtf(red[0] * (1.f / 512.f) + 1e-5f);
  out[(size_t)b * 512 + t] = d0 * inv * g[t] + bb[t];
  out[(size_t)b * 512 + t + 256] = d1 * inv * g[t + 256] + bb[t + 256];
}

__global__ __launch_bounds__(256) void select_k(
    const float* __restrict__ pwP, const float* __restrict__ pb,
    const float* __restrict__ emb, const float* __restrict__ ew,
    int* visited, int* ucount, int* complete, int* allvis, int* first, int* prev,
    float* __restrict__ ctxh, float* __restrict__ out,
    const float* __restrict__ sb_p, const float* __restrict__ rp_p, int step)
{
  int b = blockIdx.x, t = threadIdx.x;
  __shared__ float logits[512];
  __shared__ float sc[128];
  __shared__ float red[256];
  __shared__ int redi[256];
#pragma unroll
  for (int r = 0; r < 2; ++r) {
    int e = t + 256 * r;
    float s = pb[e];
#pragma unroll
    for (int s8 = 0; s8 < 8; ++s8) s += pwP[(size_t)s8 * 65536 + (size_t)b * 512 + e];
    logits[e] = s;
  }
  __syncthreads();
  if (t < Nn) {
    const float* er = emb + ((size_t)b * Nn + t) * 512;
    float s = 0.f;
    for (int e = 0; e < 512; ++e) s += logits[e] * er[e];
    int av = allvis[b];
    if (!av && visited[b * Nn + t]) s = rp_p[0];
    if (av) {
      int pv = prev[b];
      float direct = ew[(size_t)b * 10000 + (size_t)pv * 100];
      float via = ew[(size_t)b * 10000 + (size_t)pv * 100 + t] + ew[(size_t)b * 10000 + (size_t)t * 100];
      if (via < direct) s += sb_p[0] * (direct - via) / direct;
    }
    if (complete[b]) s = (t == first[b]) ? 100.f : -1e9f;
    sc[t] = s;
  }
  __syncthreads();
  float vv = (t < Nn) ? sc[t] : -3.4e38f;
  int ii = (t < Nn) ? t : 0x7fffffff;
  red[t] = vv; redi[t] = ii;
  __syncthreads();
  for (int o = 128; o > 0; o >>= 1) {
    if (t < o) {
      float v2 = red[t + o]; int i2 = redi[t + o];
      if (v2 > red[t] || (v2 == red[t] && i2 < redi[t])) { red[t] = v2; redi[t] = i2; }
    }
    __syncthreads();
  }
  float m = red[0];
  int curr = redi[0];
  __syncthreads();
  float ex = (t < Nn) ? expf(sc[t] - m) : 0.f;
  red[t] = ex; __syncthreads();
  for (int o = 128; o > 0; o >>= 1) { if (t < o) red[t] += red[t + o]; __syncthreads(); }
  float Z = red[0];
  if (t == 0) {
    float pcur = expf(sc[curr] - m) / Z;
    out[step * Bb + b] = logf(pcur + 1e-10f);
    out[(151 + step) * Bb + b] = (float)curr;
    if (!complete[b]) {
      if (!visited[b * Nn + curr]) ucount[b] = ucount[b] + 1;
      visited[b * Nn + curr] = 1;
    }
    if (ucount[b] >= Nn) allvis[b] = 1;
    if (step == 0) first[b] = curr;
    prev[b] = curr;
  }
  const float* src = emb + ((size_t)b * Nn + curr) * 512;
  ctxh[(size_t)b * 1024 + t] = src[t];
  ctxh[(size_t)b * 1024 + t + 256] = src[t + 256];
}

__global__ void final_k(const int* complete, const int* first, float* out)
{
  int b = threadIdx.x;
  out[(151 + 150) * Bb + b] = complete[b] ? 0.f : (float)first[b];
}

// ---------------------------------------------------------------------------
extern "C" void kernel_launch(void* const* d_in, const int* in_sizes, int n_in,
                              void* d_out, int out_size, void* d_ws, size_t ws_size,
                              hipStream_t stream)
{
  const float* nf      = (const float*)d_in[0];
  const float* ew      = (const float*)d_in[1];
  const float* pe      = (const float*)d_in[2];
  const float* in_w    = (const float*)d_in[3];
  const float* in_b    = (const float*)d_in[4];
  const float* enc_wq  = (const float*)d_in[5];
  const float* enc_wk  = (const float*)d_in[6];
  const float* enc_wv  = (const float*)d_in[7];
  const float* enc_wo  = (const float*)d_in[8];
  const float* enc_bq  = (const float*)d_in[9];
  const float* enc_bk  = (const float*)d_in[10];
  const float* enc_bv  = (const float*)d_in[11];
  const float* enc_bo  = (const float*)d_in[12];
  const float* enc_w1  = (const float*)d_in[13];
  const float* enc_b1  = (const float*)d_in[14];
  const float* enc_w2  = (const float*)d_in[15];
  const float* enc_b2  = (const float*)d_in[16];
  const float* ln1g    = (const float*)d_in[17];
  const float* ln1b    = (const float*)d_in[18];
  const float* ln2g    = (const float*)d_in[19];
  const float* ln2b    = (const float*)d_in[20];
  const float* wih     = (const float*)d_in[21];
  const float* whh     = (const float*)d_in[22];
  const float* bih     = (const float*)d_in[23];
  const float* bhh     = (const float*)d_in[24];
  const float* dwq     = (const float*)d_in[25];
  const float* dwk     = (const float*)d_in[26];
  const float* dwv     = (const float*)d_in[27];
  const float* dwo     = (const float*)d_in[28];
  const float* dpw     = (const float*)d_in[29];
  const float* dbq     = (const float*)d_in[30];
  const float* dbk     = (const float*)d_in[31];
  const float* dbv     = (const float*)d_in[32];
  const float* dbo     = (const float*)d_in[33];
  const float* dpb     = (const float*)d_in[34];
  const float* dlng    = (const float*)d_in[35];
  const float* dlnb    = (const float*)d_in[36];
  const float* sbp     = (const float*)d_in[37];
  const float* rpp     = (const float*)d_in[38];
  const float* done_w  = (const float*)d_in[39];
  const float* done_b  = (const float*)d_in[40];
  float* out = (float*)d_out;

  // ---- workspace carve ----
  const size_t SZ = 12800ull * 512;            // 6,553,600 elements
  float* ws = (float*)d_ws;
  float* x   = ws;                              // fp32 node emb
  float* xq  = x + SZ;                          // q / wo-out / ff2-out
  float* xk  = xq + SZ;                         // enc k -> dec K
  float* xv  = xk + SZ;                         // enc v -> FF2 partials -> dec V
  _Float16* xh = (_Float16*)(xv + SZ);          // x hi plane
  _Float16* xl = xh + SZ;                       // x lo plane
  _Float16* oh = xl + SZ;                       // attn-out hi  (alias: FF1-out hi)
  _Float16* ol = oh + SZ;                       // attn-out lo  (alias: FF1-out lo)
  _Float16* wb = ol + SZ;                       // weight planes, 6,291,456 f16
  _Float16* wqh = wb;               _Float16* wql = wqh + 262144;
  _Float16* wkh = wql + 262144;     _Float16* wkl = wkh + 262144;
  _Float16* wvh = wkl + 262144;     _Float16* wvl = wvh + 262144;
  _Float16* woh_ = wvl + 262144;    _Float16* wol_ = woh_ + 262144;
  _Float16* w1h = wol_ + 262144;    _Float16* w1l = w1h + 1048576;
  _Float16* w2h = w1l + 1048576;    _Float16* w2l = w2h + 1048576;
  float* ctxh   = (float*)(w2l + 1048576);      // 128 x 1024 [ctx | h]
  float* cbuf   = ctxh + 131072;                // 128 x 512
  float* gatesP = cbuf + 65536;                 // 2 x 128 x 2048
  float* qP     = gatesP + 524288;              // 8 x 128 x 512
  float* woP    = qP + 524288;
  float* pwP    = woP + 524288;
  float* abuf   = pwP + 524288;                 // 128 x 512
  float* dbuf   = abuf + 65536;                 // 128 x 512 dec-attn out
  int* ivis     = (int*)(dbuf + 65536);
  int* ucount   = ivis + 12800;
  int* complete = ucount + 128;
  int* allvis   = complete + 128;
  int* first    = allvis + 128;
  int* prev     = first + 128;

  // ---- encoder ----
  input_proj_k<<<25600, 256, 0, stream>>>(nf, in_w, in_b, pe, x, xh, xl);

  for (int l = 0; l < Ll; ++l) {
    const float* wq = enc_wq + (size_t)l * 262144;
    const float* wk = enc_wk + (size_t)l * 262144;
    const float* wv = enc_wv + (size_t)l * 262144;
    const float* wo = enc_wo + (size_t)l * 262144;
    const float* bq = enc_bq + (size_t)l * 512;
    const float* bk = enc_bk + (size_t)l * 512;
    const float* bv = enc_bv + (size_t)l * 512;
    const float* bo = enc_bo + (size_t)l * 512;
    const float* w1 = enc_w1 + (size_t)l * 1048576;
    const float* b1 = enc_b1 + (size_t)l * 2048;
    const float* w2 = enc_w2 + (size_t)l * 1048576;
    const float* b2 = enc_b2 + (size_t)l * 512;

    wconv_k<<<dim3(16, 16), 256, 0, stream>>>(wq, 512, 512, wqh, wql);
    wconv_k<<<dim3(16, 16), 256, 0, stream>>>(wk, 512, 512, wkh, wkl);
    wconv_k<<<dim3(16, 16), 256, 0, stream>>>(wv, 512, 512, wvh, wvl);
    wconv_k<<<dim3(16, 16), 256, 0, stream>>>(wo, 512, 512, woh_, wol_);
    wconv_k<<<dim3(64, 16), 256, 0, stream>>>(w1, 512, 2048, w1h, w1l);
    wconv_k<<<dim3(16, 64), 256, 0, stream>>>(w2, 2048, 512, w2h, w2l);

    mgemm_k<false, true, true, false><<<dim3(4, 100), 256, 0, stream>>>(
        xh, xl, 512, wqh, wql, 512, xq, nullptr, nullptr, 512, bq, 512, 0, 0);
    mgemm_k<false, true, true, false><<<dim3(4, 100), 256, 0, stream>>>(
        xh, xl, 512, wkh, wkl, 512, xk, nullptr, nullptr, 512, bk, 512, 0, 0);
    mgemm_k<false, true, true, false><<<dim3(4, 100), 256, 0, stream>>>(
        xh, xl, 512, wvh, wvl, 512, xv, nullptr, nullptr, 512, bv, 512, 0, 0);
    enc_attn_k<<<1024, 256, 0, stream>>>(xq, xk, xv, oh, ol);
    mgemm_k<false, true, true, false><<<dim3(4, 100), 256, 0, stream>>>(
        oh, ol, 512, woh_, wol_, 512, xq, nullptr, nullptr, 512, bo, 512, 0, 0);
    ln_k<<<12800, 256, 0, stream>>>(x, xq, ln1g + l * 512, ln1b + l * 512, x, xh, xl);
    for (int c = 0; c < 4; ++c) {
      mgemm_k<true, true, false, false><<<dim3(16, 25), 256, 0, stream>>>(
          xh + (size_t)c * 3200 * 512, xl + (size_t)c * 3200 * 512, 512,
          w1h, w1l, 512, nullptr, oh, ol, 2048, b1, 512, 0, 0);
      mgemm_k<false, false, true, true><<<dim3(4, 25, 4), 256, 0, stream>>>(
          oh, ol, 2048, w2h, w2l, 2048, xv, nullptr, nullptr, 512,
          nullptr, 2048, 512, 3200);
      reduce4_k<<<6400, 256, 0, stream>>>(xv, b2, xq + (size_t)c * 3200 * 512);
    }
    ln_k<<<12800, 256, 0, stream>>>(x, xq, ln2g + l * 512, ln2b + l * 512, x, xh, xl);
  }

  // ---- decode prep: K/V step-invariant ----
  wconv_k<<<dim3(16, 16), 256, 0, stream>>>(dwk, 512, 512, wqh, wql);
  wconv_k<<<dim3(16, 16), 256, 0, stream>>>(dwv, 512, 512, wkh, wkl);
  mgemm_k<false, true, true, false><<<dim3(4, 100), 256, 0, stream>>>(
      xh, xl, 512, wqh, wql, 512, xk, nullptr, nullptr, 512, dbk, 512, 0, 0);
  mgemm_k<false, true, true, false><<<dim3(4, 100), 256, 0, stream>>>(
      xh, xl, 512, wkh, wkl, 512, xv, nullptr, nullptr, 512, dbv, 512, 0, 0);
  init_k<<<128, 256, 0, stream>>>(x, ctxh, cbuf, ivis, ucount, complete, allvis, first, prev, out);

  // ---- decode loop ----
  for (int step = 0; step < STEPS; ++step) {
    gemm_k<32, 64, 16, 2, 4><<<dim3(32, 4, 2), 256, 0, stream>>>(
        ctxh, 1024, wih, whh, 512, 2048, gatesP, 2048, 128, 2048, 1024, 512);
    lstm_pw_k<<<128, 256, 0, stream>>>(gatesP, bih, bhh, ctxh, cbuf, done_w, done_b,
                                       complete, ucount, step);
    gemm_k<32, 64, 16, 2, 4><<<dim3(8, 4, 8), 256, 0, stream>>>(
        ctxh + 512, 1024, dwq, dwq, 1 << 30, 512, qP, 512, 128, 512, 512, 64);
    dec_attn_k<<<1024, 128, 0, stream>>>(qP, dbq, xk, xv, dbuf);
    gemm_k<32, 64, 16, 2, 4><<<dim3(8, 4, 8), 256, 0, stream>>>(
        dbuf, 512, dwo, dwo, 1 << 30, 512, woP, 512, 128, 512, 512, 64);
    dec_ln_k<<<128, 256, 0, stream>>>(woP, dbo, dlng, dlnb, abuf);
    gemm_k<32, 64, 16, 2, 4><<<dim3(8, 4, 8), 256, 0, stream>>>(
        abuf, 512, dpw, dpw, 1 << 30, 512, pwP, 512, 128, 512, 512, 64);
    select_k<<<128, 256, 0, stream>>>(pwP, dpb, x, ew, ivis, ucount, complete, allvis,
                                      first, prev, ctxh, out, sbp, rpp, step);
  }
  final_k<<<1, 128, 0, stream>>>(complete, first, out);
}